// Round 1
// baseline (573.418 us; speedup 1.0000x reference)
//
#include <hip/hip_runtime.h>
#include <math.h>
#include <stdint.h>

// RGWRP: per row (B*C = 16384 rows of HW = 4096 floats):
//   top-905 values sorted descending, weighted by d^r (d = 0.01^(1/904)),
//   summed, divided by sum of weights.
//
// Strategy: radix-select threshold prefix so that candidate count <= 1024,
// gather candidates to LDS, bitonic-sort 1024, weighted-sum first 905.

#define K_TOP     905
#define ROW_LEN   4096
#define THREADS   256
#define NREG      16      // ROW_LEN / THREADS
#define CAND      1024
#define HIST_PAD  264     // 256 bins + pad so per-wave copies land on different banks

__device__ __forceinline__ unsigned f2k(float f) {
  unsigned u = __float_as_uint(f);
  return (u & 0x80000000u) ? ~u : (u | 0x80000000u);
}
__device__ __forceinline__ float k2f(unsigned k) {
  unsigned u = (k & 0x80000000u) ? (k & 0x7fffffffu) : ~k;
  return __uint_as_float(u);
}

__global__ __launch_bounds__(THREADS, 4) void rgwrp_kernel(
    const float* __restrict__ x, float* __restrict__ out,
    float wExpC, float invSumW) {
  const int row  = blockIdx.x;
  const int tid  = threadIdx.x;
  const int lane = tid & 63;
  const int wave = tid >> 6;

  __shared__ unsigned hist[4][HIST_PAD];
  __shared__ unsigned cand[CAND];
  __shared__ unsigned sb0, sA, sC;
  __shared__ unsigned nGather;
  __shared__ float    wsum[4];

  // ---- load 16 elements/thread (coalesced float4) and convert to keys ----
  unsigned k[NREG];
  const float4* xr = (const float4*)(x + (size_t)row * ROW_LEN);
#pragma unroll
  for (int i = 0; i < 4; ++i) {
    float4 v = xr[i * THREADS + tid];
    k[i * 4 + 0] = f2k(v.x);
    k[i * 4 + 1] = f2k(v.y);
    k[i * 4 + 2] = f2k(v.z);
    k[i * 4 + 3] = f2k(v.w);
  }

  // ---- MSD radix select: refine prefix until candidate count <= 1024 ----
  unsigned prefix = 0;   // value of bits above `shift`
  unsigned gAbove = 0;   // count of keys with (key>>shift) > prefix
  unsigned nSel   = 0;   // candidate count at stop
  unsigned kloKey = 0;   // gather threshold (normal case)
  int shift = 24;
  bool tieCase = false;

  for (int round = 0; round < 4; ++round) {
    // clear histograms
    for (int i = tid; i < 4 * HIST_PAD; i += THREADS)
      (&hist[0][0])[i] = 0u;
    __syncthreads();

#pragma unroll
    for (int i = 0; i < NREG; ++i) {
      unsigned key = k[i];
      bool match = (round == 0) || ((key >> (shift + 8)) == prefix);
      if (match) atomicAdd(&hist[wave][(key >> shift) & 0xFFu], 1u);
    }
    __syncthreads();

    if (wave == 0) {
      // lane owns bins 4*lane .. 4*lane+3
      int b = lane << 2;
      unsigned t0 = hist[0][b+0] + hist[1][b+0] + hist[2][b+0] + hist[3][b+0];
      unsigned t1 = hist[0][b+1] + hist[1][b+1] + hist[2][b+1] + hist[3][b+1];
      unsigned t2 = hist[0][b+2] + hist[1][b+2] + hist[2][b+2] + hist[3][b+2];
      unsigned t3 = hist[0][b+3] + hist[1][b+3] + hist[2][b+3] + hist[3][b+3];
      unsigned own = t0 + t1 + t2 + t3;
      unsigned s = own;
      // inclusive suffix-scan across lanes (sum over lanes >= lane)
#pragma unroll
      for (int off = 1; off < 64; off <<= 1) {
        unsigned t = __shfl_down(s, off);
        s += (lane + off < 64) ? t : 0u;
      }
      unsigned A = s - own;  // count in lanes strictly above this lane's bins
      unsigned kk = (unsigned)K_TOP - gAbove;
      unsigned tq[4] = { t0, t1, t2, t3 };
#pragma unroll
      for (int q = 3; q >= 0; --q) {
        unsigned c = tq[q];
        if (A < kk && kk <= A + c) { sb0 = (unsigned)(b + q); sA = A; sC = c; }
        A += c;
      }
    }
    __syncthreads();

    unsigned b0 = sb0, A = sA, c = sC;
    gAbove += A;
    prefix = (prefix << 8) | b0;
    nSel = gAbove + c;
    if (nSel <= CAND) { kloKey = prefix << shift; break; }
    if (shift == 0)   { tieCase = true; break; }
    shift -= 8;
  }

  // ---- gather candidates into LDS (ballot-aggregated) ----
  if (tid == 0) nGather = 0u;
  __syncthreads();
  {
    unsigned thr = tieCase ? prefix : kloKey;
#pragma unroll
    for (int i = 0; i < NREG; ++i) {
      unsigned key = k[i];
      bool pred = tieCase ? (key > thr) : (key >= thr);
      unsigned long long m = __ballot(pred);
      if (m) {
        int leader = __ffsll(m) - 1;
        unsigned cnt = (unsigned)__popcll(m);
        unsigned pre = (unsigned)__popcll(m & ((1ull << lane) - 1ull));
        unsigned base = 0;
        if (lane == leader) base = atomicAdd(&nGather, cnt);
        base = __shfl(base, leader);
        if (pred) cand[base + pre] = key;
      }
    }
  }
  __syncthreads();

  // ---- pad: tie-fill with exact key up to 905, zeros to 1024 ----
  {
    unsigned n0 = nGather;
    unsigned fillEnd = tieCase ? (unsigned)K_TOP : n0;
    for (unsigned i = tid; i < CAND; i += THREADS) {
      if (i >= fillEnd)      cand[i] = 0u;
      else if (i >= n0)      cand[i] = prefix;  // exact threshold key copies
    }
  }
  __syncthreads();

  // ---- bitonic sort 1024 keys, descending ----
  for (unsigned kk = 2; kk <= CAND; kk <<= 1) {
    for (unsigned j = kk >> 1; j > 0; j >>= 1) {
#pragma unroll
      for (unsigned e = tid; e < CAND / 2; e += THREADS) {
        unsigned i = ((e & ~(j - 1)) << 1) | (e & (j - 1));
        unsigned p = i | j;
        unsigned a = cand[i], b = cand[p];
        // (i & kk)==0 -> descending compare-exchange
        bool doSwap = ((i & kk) == 0u) == (a < b);
        if (doSwap) { cand[i] = b; cand[p] = a; }
      }
      __syncthreads();
    }
  }

  // ---- weighted sum of top 905 ----
  float local = 0.f;
  for (int r = tid; r < K_TOP; r += THREADS) {
    float v = k2f(cand[r]);
    float w = exp2f((float)r * wExpC);
    local += v * w;
  }
#pragma unroll
  for (int off = 32; off > 0; off >>= 1)
    local += __shfl_down(local, off);
  if (lane == 0) wsum[wave] = local;
  __syncthreads();
  if (tid == 0)
    out[row] = (wsum[0] + wsum[1] + wsum[2] + wsum[3]) * invSumW;
}

extern "C" void kernel_launch(void* const* d_in, const int* in_sizes, int n_in,
                              void* d_out, int out_size, void* d_ws, size_t ws_size,
                              hipStream_t stream) {
  (void)in_sizes; (void)n_in; (void)d_ws; (void)ws_size; (void)out_size;
  const float* x = (const float*)d_in[0];
  float* out = (float*)d_out;

  const double d    = pow(0.01, 1.0 / 904.0);
  const double sumW = (1.0 - pow(0.01, 905.0 / 904.0)) / (1.0 - d);
  const float wExpC   = (float)(log2(d));
  const float invSumW = (float)(1.0 / sumW);

  rgwrp_kernel<<<16384, THREADS, 0, stream>>>(x, out, wExpC, invSumW);
}